// Round 10
// baseline (1554.014 us; speedup 1.0000x reference)
//
#include <hip/hip_runtime.h>

#define D 128
#define NG 64
#define NPB 256       // nodes per bucket (bucket = dst >> 8)
#define MAXBK 512     // max buckets (n <= 131072)
#define CAPB 8192     // fixed bucket capacity (mean 4096, sigma 64 -> never overflows)
#define PCHUNK 4096   // edges per partition block
#define NPASS 4       // feature-split passes (32 features each)
#define LDA 136       // padded LDS row (bf16) for GEMM
#define AGP 33        // padded feature stride in k_agg accumulator

typedef unsigned int uint;
typedef unsigned short ushort_t;
typedef unsigned char uchar_t;
typedef float v2f __attribute__((ext_vector_type(2)));
typedef short s8v __attribute__((ext_vector_type(8)));   // 8 bf16 MFMA A/B frag
typedef float f4v __attribute__((ext_vector_type(4)));   // MFMA C/D frag

// bf16 round-to-nearest-even
__device__ __forceinline__ uint bfr(float x) {
    uint u = __float_as_uint(x);
    return (u + 0x7FFFu + ((u >> 16) & 1u)) >> 16;
}

// ---------------- init + W1 transpose->bf16 (one kernel) ----------------
__global__ __launch_bounds__(256) void k_initprep(const float* __restrict__ W,
                                                  short* __restrict__ W1T,
                                                  int* __restrict__ gcur,
                                                  float* __restrict__ psum,
                                                  float* __restrict__ pcnt, int NBK) {
    int idx = blockIdx.x * 256 + threadIdx.x;  // 0..16383
    int nn = idx >> 7, kk = idx & 127;
    W1T[idx] = (short)bfr(W[kk * D + nn]);
    if (idx < NBK) gcur[idx] = idx * CAPB;
    if (idx < NG * 4) psum[idx] = 0.f;
    if (idx < NG) pcnt[idx] = 0.f;
}

// ---------------- phase-1 partition into fixed-capacity buckets (LDS reorder) ----------------
// entry = (dst&255)<<17 | src  (src < 2^17)
__global__ __launch_bounds__(256) void k_part(const int* __restrict__ edge,
                                              int* __restrict__ gcur, int* __restrict__ p1,
                                              int E, int NBK) {
    __shared__ int hist[MAXBK], scn[MAXBK], curb[MAXBK], fixb[MAXBK];
    __shared__ int ps[256];
    __shared__ int sortb[PCHUNK];
    __shared__ ushort_t sbkt[PCHUNK];
    int tid = threadIdx.x;
    for (int i = tid; i < MAXBK; i += 256) { hist[i] = 0; curb[i] = 0; }
    __syncthreads();
    int lo = blockIdx.x * PCHUNK;
    int hi = min(lo + PCHUNK, E);
    int cnt = hi - lo;
    for (int e = lo + tid; e < hi; e += 256) atomicAdd(&hist[edge[E + e] >> 8], 1);
    __syncthreads();
    int a = hist[2 * tid], b = hist[2 * tid + 1];
    ps[tid] = a + b;
    __syncthreads();
    for (int o = 1; o < 256; o <<= 1) {
        int x = (tid >= o) ? ps[tid - o] : 0;
        __syncthreads();
        ps[tid] += x;
        __syncthreads();
    }
    int pe = ps[tid] - (a + b);
    scn[2 * tid] = pe;
    scn[2 * tid + 1] = pe + a;
    __syncthreads();
    for (int bk = tid; bk < NBK; bk += 256)
        if (hist[bk]) fixb[bk] = atomicAdd(&gcur[bk], hist[bk]) - scn[bk];
    __syncthreads();
    for (int e = lo + tid; e < hi; e += 256) {
        int s = edge[e];
        int d2 = edge[E + e];
        int bk = d2 >> 8;
        int r = scn[bk] + atomicAdd(&curb[bk], 1);
        sortb[r] = ((d2 & 255) << 17) | s;
        sbkt[r] = (ushort_t)bk;
    }
    __syncthreads();
    for (int p = tid; p < cnt; p += 256) {
        int bk = sbkt[p];
        p1[fixb[bk] + p] = sortb[p];
    }
}

// ---------------- per-bucket degree histogram -> dinv ----------------
__global__ __launch_bounds__(256) void k_deg(const int* __restrict__ p1,
                                             const int* __restrict__ gcur,
                                             float* __restrict__ dinv, int n) {
    __shared__ int cnt[256];
    int tid = threadIdx.x;
    int b = blockIdx.x;
    cnt[tid] = 0;
    __syncthreads();
    int base = b * CAPB, end = gcur[b];
    for (int p = base + tid; p < end; p += 256) atomicAdd(&cnt[p1[p] >> 17], 1);
    __syncthreads();
    int node = (b << 8) + tid;
    if (node < n) dinv[node] = rsqrtf((float)(cnt[tid] + 1));
}

// ---------------- GEMM1 (MFMA bf16): Hs = dinv*(X @ W1), fp8 out, chunk-major ----------------
__global__ __launch_bounds__(256) void k_gemm_mfma(const float* __restrict__ X,
                                                   const short* __restrict__ W1T,
                                                   const float* __restrict__ dinv,
                                                   uchar_t* __restrict__ H8b, int M) {
    __shared__ short sA[128 * LDA];
    __shared__ short sB[128 * LDA];
    __shared__ float sDinv[128];
    const int tid = threadIdx.x;
    const int blockM = blockIdx.x * 128;

    if (tid < 128) {
        int gm = blockM + tid;
        sDinv[tid] = (gm < M) ? dinv[gm] : 0.f;
    }
    {
        int c = tid & 31, g = tid >> 5;
#pragma unroll
        for (int i = 0; i < 16; ++i) {
            int r = g + i * 8;
            int gm = blockM + r;
            float4 v = make_float4(0, 0, 0, 0);
            if (gm < M) v = *(const float4*)&X[(size_t)gm * D + c * 4];
            uint lo = bfr(v.x) | (bfr(v.y) << 16);
            uint hi = bfr(v.z) | (bfr(v.w) << 16);
            *(uint2*)&sA[r * LDA + c * 4] = make_uint2(lo, hi);
        }
    }
    {
        int nn = tid >> 1, seg = tid & 1;
        const short* src = W1T + nn * 128 + seg * 64;
        short* dst = &sB[nn * LDA + seg * 64];
#pragma unroll
        for (int i = 0; i < 8; ++i)
            *(int4*)&dst[i * 8] = *(const int4*)&src[i * 8];
    }
    __syncthreads();

    const int wv = tid >> 6;
    const int lane = tid & 63;
    const int m0w = (wv >> 1) * 64, n0w = (wv & 1) * 64;
    const int mrow = lane & 15;
    const int quad = lane >> 4;

    f4v acc[4][4];
#pragma unroll
    for (int mi = 0; mi < 4; ++mi)
#pragma unroll
        for (int ni = 0; ni < 4; ++ni) acc[mi][ni] = (f4v)(0.f);

#pragma unroll
    for (int ks = 0; ks < 4; ++ks) {
        s8v af[4], bf[4];
#pragma unroll
        for (int mi = 0; mi < 4; ++mi)
            af[mi] = *(const s8v*)&sA[(m0w + mi * 16 + mrow) * LDA + ks * 32 + quad * 8];
#pragma unroll
        for (int ni = 0; ni < 4; ++ni)
            bf[ni] = *(const s8v*)&sB[(n0w + ni * 16 + mrow) * LDA + ks * 32 + quad * 8];
#pragma unroll
        for (int mi = 0; mi < 4; ++mi)
#pragma unroll
            for (int ni = 0; ni < 4; ++ni)
                acc[mi][ni] = __builtin_amdgcn_mfma_f32_16x16x32_bf16(af[mi], bf[ni], acc[mi][ni], 0, 0, 0);
    }

#pragma unroll
    for (int mi = 0; mi < 4; ++mi) {
#pragma unroll
        for (int r = 0; r < 4; ++r) {
            int lrow = m0w + mi * 16 + quad * 4 + r;
            int gm = blockM + lrow;
            if (gm >= M) continue;
            float di = sDinv[lrow];
#pragma unroll
            for (int ni = 0; ni < 4; ++ni) {
                int col = n0w + ni * 16 + mrow;
                float v = acc[mi][ni][r] * di;
                uint p = __builtin_amdgcn_cvt_pk_fp8_f32(v, v, 0u, false);
                H8b[((size_t)(col >> 5) * M + gm) * 32 + (col & 31)] = (uchar_t)(p & 0xFF);
            }
        }
    }
}

// ---------------- layer-1 aggregation, EDGE-WISE per bucket, LDS accumulator ----------------
// One block per bucket per pass. acc[256][33] fp32. Self term seeds acc; edges ds_add.
// Epilogue: v = di*acc + b1, leaky, @W2 slice -> zpart (pass 3 folds the final reduce).
__global__ __launch_bounds__(256) void k_agg(const uint* __restrict__ Hsu,
                                             const int* __restrict__ p1,
                                             const int* __restrict__ gcur,
                                             const float* __restrict__ dinv,
                                             const float* __restrict__ b1,
                                             const float* __restrict__ W2,
                                             float4* __restrict__ zpart,
                                             float4* __restrict__ zs,
                                             int n, int p) {
    __shared__ float acc[NPB * AGP];  // 33.8 KB
    __shared__ float sW[128];
    __shared__ float sb[32];
    int tid = threadIdx.x;
    int b = blockIdx.x;
    int node0 = b << 8;
    if (tid < 128) sW[tid] = W2[p * 128 + tid];
    if (tid < 32) sb[tid] = b1[p * 32 + tid];
    const uint* T = Hsu + (size_t)p * n * 8;
    // seed with self term (Hs pre-scaled by dinv)
    {
        int node = node0 + tid;
        float* a = &acc[tid * AGP];
        if (node < n) {
            const uint* row = T + ((size_t)node << 3);
#pragma unroll
            for (int k = 0; k < 8; ++k) {
                uint r = row[k];
                v2f lo = __builtin_amdgcn_cvt_pk_f32_fp8(r, false);
                v2f hi = __builtin_amdgcn_cvt_pk_f32_fp8(r, true);
                a[4 * k + 0] = lo.x;
                a[4 * k + 1] = lo.y;
                a[4 * k + 2] = hi.x;
                a[4 * k + 3] = hi.y;
            }
        } else {
#pragma unroll
            for (int k = 0; k < 32; ++k) a[k] = 0.f;
        }
    }
    __syncthreads();
    // edge-wise accumulate: 8 lanes per entry, 4 feats per lane
    int base = b * CAPB, end = gcur[b];
    int k8 = tid & 7;
    int g8 = tid >> 3;
    for (int q = base + g8; q < end; q += 32) {
        int v = p1[q];
        int src = v & 0x1FFFF;
        int dl = v >> 17;
        uint r = T[((size_t)src << 3) + k8];
        v2f lo = __builtin_amdgcn_cvt_pk_f32_fp8(r, false);
        v2f hi = __builtin_amdgcn_cvt_pk_f32_fp8(r, true);
        float* a = &acc[dl * AGP + k8 * 4];
        atomicAdd(a + 0, lo.x);
        atomicAdd(a + 1, lo.y);
        atomicAdd(a + 2, hi.x);
        atomicAdd(a + 3, hi.y);
    }
    __syncthreads();
    // per-node epilogue
    int node = node0 + tid;
    if (node < n) {
        float di = dinv[node];
        const float* a = &acc[tid * AGP];
        float o0 = 0.f, o1 = 0.f, o2 = 0.f, o3 = 0.f;
#pragma unroll
        for (int f = 0; f < 32; ++f) {
            float v = di * a[f] + sb[f];
            v = v >= 0.f ? v : 0.01f * v;
            o0 += v * sW[f * 4 + 0];
            o1 += v * sW[f * 4 + 1];
            o2 += v * sW[f * 4 + 2];
            o3 += v * sW[f * 4 + 3];
        }
        if (p < 3) {
            zpart[(size_t)p * n + node] = make_float4(o0, o1, o2, o3);
        } else {
            float4 q0 = zpart[node];
            float4 q1 = zpart[(size_t)n + node];
            float4 q2 = zpart[(size_t)2 * n + node];
            zs[node] = make_float4(di * (o0 + q0.x + q1.x + q2.x),
                                   di * (o1 + q0.y + q1.y + q2.y),
                                   di * (o2 + q0.z + q1.z + q2.z),
                                   di * (o3 + q0.w + q1.w + q2.w));
        }
    }
}

// ---------------- layer-2 agg + mean-pool, EDGE-WISE, 2 blocks per bucket ----------------
__global__ __launch_bounds__(256) void k_pool2(const int* __restrict__ p1,
                                               const int* __restrict__ gcur,
                                               const float4* __restrict__ zs,
                                               const float* __restrict__ dinv,
                                               const int* __restrict__ batch,
                                               float* __restrict__ psum, float* __restrict__ pcnt,
                                               int n) {
    __shared__ float ls[NG * 4];
    __shared__ float lc[NG];
    __shared__ float dinvd[NPB];
    __shared__ int gl[NPB];
    int tid = threadIdx.x;
    int b = blockIdx.x >> 1;
    int half = blockIdx.x & 1;
    int node0 = b << 8;
    int node = node0 + tid;
    ls[tid] = 0.f;
    if (tid < NG) lc[tid] = 0.f;
    bool valid = node < n;
    float di = valid ? dinv[node] : 0.f;
    int g = valid ? batch[node] : -1;
    dinvd[tid] = di;
    gl[tid] = g;
    __syncthreads();
    float a0 = 0.f, a1 = 0.f, a2 = 0.f, a3 = 0.f;
    int cg = -1;
    if (half == 0 && valid) {
        float4 zv = zs[node];
        cg = g;
        a0 = di * zv.x; a1 = di * zv.y; a2 = di * zv.z; a3 = di * zv.w;
        atomicAdd(&lc[g], 1.f);
    }
    int base = b * CAPB;
    int cnt = gcur[b] - base;
    int mid = cnt >> 1;
    int s0 = base + (half ? mid : 0);
    int s1 = base + (half ? cnt : mid);
    for (int p = s0 + tid; p < s1; p += 1024) {
        int vv[4];
        float4 zb[4];
        int nb = 0;
#pragma unroll
        for (int k = 0; k < 4; ++k) {
            int q = p + k * 256;
            if (q < s1) vv[nb++] = p1[q];
        }
#pragma unroll
        for (int k = 0; k < 4; ++k)
            if (k < nb) zb[k] = zs[vv[k] & 0x1FFFF];
#pragma unroll
        for (int k = 0; k < 4; ++k) {
            if (k >= nb) continue;
            int dl = vv[k] >> 17;
            float w = dinvd[dl];
            int eg = gl[dl];
            if (eg != cg) {
                if (cg >= 0) {
                    atomicAdd(&ls[cg * 4 + 0], a0);
                    atomicAdd(&ls[cg * 4 + 1], a1);
                    atomicAdd(&ls[cg * 4 + 2], a2);
                    atomicAdd(&ls[cg * 4 + 3], a3);
                }
                cg = eg;
                a0 = a1 = a2 = a3 = 0.f;
            }
            a0 += w * zb[k].x; a1 += w * zb[k].y; a2 += w * zb[k].z; a3 += w * zb[k].w;
        }
    }
    if (cg >= 0) {
        atomicAdd(&ls[cg * 4 + 0], a0);
        atomicAdd(&ls[cg * 4 + 1], a1);
        atomicAdd(&ls[cg * 4 + 2], a2);
        atomicAdd(&ls[cg * 4 + 3], a3);
    }
    __syncthreads();
    atomicAdd(&psum[tid], ls[tid]);
    if (tid < NG) atomicAdd(&pcnt[tid], lc[tid]);
}

// ---------------- final: pooled = psum/cnt + b2; softmax over 4 ----------------
__global__ void k_final(const float* __restrict__ psum, const float* __restrict__ pcnt,
                        const float* __restrict__ b2, float* __restrict__ out) {
    int g = threadIdx.x;  // 64 threads
    float c = fmaxf(pcnt[g], 1.f);
    float inv = 1.f / c;
    float l0 = psum[g * 4 + 0] * inv + b2[0];
    float l1 = psum[g * 4 + 1] * inv + b2[1];
    float l2 = psum[g * 4 + 2] * inv + b2[2];
    float l3 = psum[g * 4 + 3] * inv + b2[3];
    float m = fmaxf(fmaxf(l0, l1), fmaxf(l2, l3));
    float e0 = expf(l0 - m), e1 = expf(l1 - m), e2 = expf(l2 - m), e3 = expf(l3 - m);
    float s = 1.f / (e0 + e1 + e2 + e3);
    *(float4*)&out[g * 4] = make_float4(e0 * s, e1 * s, e2 * s, e3 * s);
}

extern "C" void kernel_launch(void* const* d_in, const int* in_sizes, int n_in,
                              void* d_out, int out_size, void* d_ws, size_t ws_size,
                              hipStream_t stream) {
    const float* X = (const float*)d_in[0];
    const int* edge = (const int*)d_in[1];
    const int* batch = (const int*)d_in[2];
    const float* W1 = (const float*)d_in[3];
    const float* b1 = (const float*)d_in[4];
    const float* W2 = (const float*)d_in[5];
    const float* b2 = (const float*)d_in[6];
    float* out = (float*)d_out;
    const int n = in_sizes[2];      // 100000
    const int E = in_sizes[1] / 2;  // 1600000
    const int NBK = (n + NPB - 1) / NPB;  // 391

    // ws: Hs[n*32 uint] | p1[NBK*CAPB] | zpart[4n float4] | zs[n float4]
    //   | dinv[n] | W1T[16384 short] | gcur[512] | psum[256] | pcnt[64]
    uint* Hs = (uint*)d_ws;
    int* p1 = (int*)(Hs + (size_t)n * 32);
    float4* zpart = (float4*)(p1 + (size_t)NBK * CAPB);
    float4* zs = zpart + (size_t)NPASS * n;
    float* dinv = (float*)(zs + n);
    short* W1T = (short*)(dinv + n);
    int* gcur = (int*)(W1T + 16384);
    float* psum = (float*)(gcur + MAXBK);
    float* pcnt = psum + NG * 4;

    const int NP = (E + PCHUNK - 1) / PCHUNK;  // 391

    k_initprep<<<64, 256, 0, stream>>>(W1, W1T, gcur, psum, pcnt, NBK);
    k_part<<<NP, 256, 0, stream>>>(edge, gcur, p1, E, NBK);
    k_deg<<<NBK, 256, 0, stream>>>(p1, gcur, dinv, n);

    k_gemm_mfma<<<(n + 127) / 128, 256, 0, stream>>>(X, W1T, dinv, (uchar_t*)Hs, n);

    for (int p = 0; p < NPASS; ++p)
        k_agg<<<NBK, 256, 0, stream>>>(Hs, p1, gcur, dinv, b1, W2, zpart, zs, n, p);

    k_pool2<<<NBK * 2, 256, 0, stream>>>(p1, gcur, zs, dinv, batch, psum, pcnt, n);
    k_final<<<1, 64, 0, stream>>>(psum, pcnt, b2, out);
}

// Round 11
// 241.950 us; speedup vs baseline: 6.4229x; 6.4229x over previous
//
#include <hip/hip_runtime.h>

#define D 128
#define NG 64
#define NPB 256       // nodes per bucket (bucket = dst >> 8)
#define MAXBK 512     // max buckets (n <= 131072)
#define CAPB 8192     // fixed bucket capacity (mean 4096, sigma 64 -> never overflows)
#define PCHUNK 4096   // edges per partition block
#define PLCAP 5376    // k_place LDS out capacity
#define ENTCAP 21     // register-cached entries per thread in k_place
#define NPASS 4       // feature-split passes (32 features each)
#define LDA 136       // padded LDS row (bf16) for GEMM

typedef unsigned int uint;
typedef unsigned short ushort_t;
typedef unsigned char uchar_t;
typedef float v2f __attribute__((ext_vector_type(2)));
typedef short s8v __attribute__((ext_vector_type(8)));   // 8 bf16 MFMA A/B frag
typedef float f4v __attribute__((ext_vector_type(4)));   // MFMA C/D frag

// bf16 round-to-nearest-even
__device__ __forceinline__ uint bfr(float x) {
    uint u = __float_as_uint(x);
    return (u + 0x7FFFu + ((u >> 16) & 1u)) >> 16;
}

// ---------------- init: W1->bf16 transposed + gcur bases ----------------
__global__ __launch_bounds__(256) void k_init(const float* __restrict__ W,
                                              short* __restrict__ W1T,
                                              int* __restrict__ gcur, int NBK) {
    int idx = blockIdx.x * 256 + threadIdx.x;  // 0..16383
    int nn = idx >> 7, kk = idx & 127;
    W1T[idx] = (short)bfr(W[kk * D + nn]);
    if (idx < NBK) gcur[idx] = idx * CAPB;
}

// ---------------- phase-1 partition into fixed-capacity buckets (LDS reorder) ----------------
// entry = (dst&255)<<17 | src  (src < 2^17)
__global__ __launch_bounds__(256) void k_part(const int* __restrict__ edge,
                                              int* __restrict__ gcur, int* __restrict__ p1,
                                              int E, int NBK) {
    __shared__ int hist[MAXBK], scn[MAXBK], curb[MAXBK], fixb[MAXBK];
    __shared__ int ps[256];
    __shared__ int sortb[PCHUNK];
    __shared__ ushort_t sbkt[PCHUNK];
    int tid = threadIdx.x;
    for (int i = tid; i < MAXBK; i += 256) { hist[i] = 0; curb[i] = 0; }
    __syncthreads();
    int lo = blockIdx.x * PCHUNK;
    int hi = min(lo + PCHUNK, E);
    int cnt = hi - lo;
    for (int e = lo + tid; e < hi; e += 256) atomicAdd(&hist[edge[E + e] >> 8], 1);
    __syncthreads();
    int a = hist[2 * tid], b = hist[2 * tid + 1];
    ps[tid] = a + b;
    __syncthreads();
    for (int o = 1; o < 256; o <<= 1) {
        int x = (tid >= o) ? ps[tid - o] : 0;
        __syncthreads();
        ps[tid] += x;
        __syncthreads();
    }
    int pe = ps[tid] - (a + b);
    scn[2 * tid] = pe;
    scn[2 * tid + 1] = pe + a;
    __syncthreads();
    for (int bk = tid; bk < NBK; bk += 256)
        if (hist[bk]) fixb[bk] = atomicAdd(&gcur[bk], hist[bk]) - scn[bk];
    __syncthreads();
    for (int e = lo + tid; e < hi; e += 256) {
        int s = edge[e];
        int d2 = edge[E + e];
        int bk = d2 >> 8;
        int r = scn[bk] + atomicAdd(&curb[bk], 1);
        sortb[r] = ((d2 & 255) << 17) | s;
        sbkt[r] = (ushort_t)bk;
    }
    __syncthreads();
    for (int p = tid; p < cnt; p += 256) {
        int bk = sbkt[p];
        p1[fixb[bk] + p] = sortb[p];
    }
}

// ---------------- phase-2 place: per-bucket CSR order; emits offdeg + dinv ----------------
__global__ __launch_bounds__(256) void k_place(const int* __restrict__ p1,
                                               const int* __restrict__ gcur,
                                               int* __restrict__ ed, int2* __restrict__ offdeg,
                                               float* __restrict__ dinv, int n) {
    __shared__ int cnts[256], scn[256], cur[256];
    __shared__ int outb[PLCAP];
    int tid = threadIdx.x;
    int b = blockIdx.x;
    int base = b * CAPB;
    int cnt = gcur[b] - base;
    int end = base + cnt;
    int node0 = b << 8;
    cnts[tid] = 0;
    cur[tid] = 0;
    __syncthreads();
    int ent[ENTCAP];
    int ne = 0;
    for (int p = base + tid; p < end; p += 256) {
        int v = p1[p];
        if (ne < ENTCAP) ent[ne] = v;
        ne++;
        atomicAdd(&cnts[v >> 17], 1);
    }
    __syncthreads();
    int v0 = cnts[tid];
    scn[tid] = v0;
    __syncthreads();
    for (int o = 1; o < 256; o <<= 1) {
        int x = (tid >= o) ? scn[tid - o] : 0;
        __syncthreads();
        scn[tid] += x;
        __syncthreads();
    }
    int excl = scn[tid] - v0;
    int node = node0 + tid;
    if (node < n) {
        offdeg[node] = make_int2(base + excl, v0);
        dinv[node] = rsqrtf((float)(v0 + 1));
    }
    scn[tid] = excl;
    __syncthreads();
    int m = (ne < ENTCAP) ? ne : ENTCAP;
    for (int k = 0; k < m; ++k) {
        int v = ent[k];
        int l = v >> 17;
        int r = scn[l] + atomicAdd(&cur[l], 1);
        if (r < PLCAP) outb[r] = v & 0x1FFFF;
        else ed[base + r] = v & 0x1FFFF;
    }
    for (int p = base + tid + ENTCAP * 256; p < end; p += 256) {
        int v = p1[p];
        int l = v >> 17;
        int r = scn[l] + atomicAdd(&cur[l], 1);
        if (r < PLCAP) outb[r] = v & 0x1FFFF;
        else ed[base + r] = v & 0x1FFFF;
    }
    __syncthreads();
    int lim = (cnt < PLCAP) ? cnt : PLCAP;
    for (int p = tid; p < lim; p += 256) ed[base + p] = outb[p];
}

// ---------------- GEMM1 (MFMA bf16): Hs = dinv*(X @ W1), fp8 out, chunk-major ----------------
__global__ __launch_bounds__(256) void k_gemm_mfma(const float* __restrict__ X,
                                                   const short* __restrict__ W1T,
                                                   const float* __restrict__ dinv,
                                                   uchar_t* __restrict__ H8b, int M) {
    __shared__ short sA[128 * LDA];
    __shared__ short sB[128 * LDA];
    __shared__ float sDinv[128];
    const int tid = threadIdx.x;
    const int blockM = blockIdx.x * 128;

    if (tid < 128) {
        int gm = blockM + tid;
        sDinv[tid] = (gm < M) ? dinv[gm] : 0.f;
    }
    {
        int c = tid & 31, g = tid >> 5;
#pragma unroll
        for (int i = 0; i < 16; ++i) {
            int r = g + i * 8;
            int gm = blockM + r;
            float4 v = make_float4(0, 0, 0, 0);
            if (gm < M) v = *(const float4*)&X[(size_t)gm * D + c * 4];
            uint lo = bfr(v.x) | (bfr(v.y) << 16);
            uint hi = bfr(v.z) | (bfr(v.w) << 16);
            *(uint2*)&sA[r * LDA + c * 4] = make_uint2(lo, hi);
        }
    }
    {
        int nn = tid >> 1, seg = tid & 1;
        const short* src = W1T + nn * 128 + seg * 64;
        short* dst = &sB[nn * LDA + seg * 64];
#pragma unroll
        for (int i = 0; i < 8; ++i)
            *(int4*)&dst[i * 8] = *(const int4*)&src[i * 8];
    }
    __syncthreads();

    const int wv = tid >> 6;
    const int lane = tid & 63;
    const int m0w = (wv >> 1) * 64, n0w = (wv & 1) * 64;
    const int mrow = lane & 15;
    const int quad = lane >> 4;

    f4v acc[4][4];
#pragma unroll
    for (int mi = 0; mi < 4; ++mi)
#pragma unroll
        for (int ni = 0; ni < 4; ++ni) acc[mi][ni] = (f4v)(0.f);

#pragma unroll
    for (int ks = 0; ks < 4; ++ks) {
        s8v af[4], bf[4];
#pragma unroll
        for (int mi = 0; mi < 4; ++mi)
            af[mi] = *(const s8v*)&sA[(m0w + mi * 16 + mrow) * LDA + ks * 32 + quad * 8];
#pragma unroll
        for (int ni = 0; ni < 4; ++ni)
            bf[ni] = *(const s8v*)&sB[(n0w + ni * 16 + mrow) * LDA + ks * 32 + quad * 8];
#pragma unroll
        for (int mi = 0; mi < 4; ++mi)
#pragma unroll
            for (int ni = 0; ni < 4; ++ni)
                acc[mi][ni] = __builtin_amdgcn_mfma_f32_16x16x32_bf16(af[mi], bf[ni], acc[mi][ni], 0, 0, 0);
    }

#pragma unroll
    for (int mi = 0; mi < 4; ++mi) {
#pragma unroll
        for (int r = 0; r < 4; ++r) {
            int lrow = m0w + mi * 16 + quad * 4 + r;
            int gm = blockM + lrow;
            if (gm >= M) continue;
            float di = sDinv[lrow];
#pragma unroll
            for (int ni = 0; ni < 4; ++ni) {
                int col = n0w + ni * 16 + mrow;
                float v = acc[mi][ni][r] * di;
                uint p = __builtin_amdgcn_cvt_pk_fp8_f32(v, v, 0u, false);
                H8b[((size_t)(col >> 5) * M + gm) * 32 + (col & 31)] = (uchar_t)(p & 0xFF);
            }
        }
    }
}

// ---------------- gather, ALL passes in one dispatch: pass = blockIdx & 3 ----------------
// Under round-robin blockIdx->XCD, XCD x only touches pass (x&3)'s 3.2MB table ->
// L2-resident per XCD (heuristic only; correctness is mapping-independent).
// 8 lanes per node, 4 features per lane via one uint (4 fp8).
__global__ __launch_bounds__(256) void k_gather(const uint* __restrict__ Hsu,
                                                const int2* __restrict__ offdeg,
                                                const int* __restrict__ ed,
                                                const float* __restrict__ dinv,
                                                const float* __restrict__ b1,
                                                const float* __restrict__ W2,
                                                float4* __restrict__ zpart,
                                                int n) {
    __shared__ float sW[128];  // W2 slice [32][4]
    __shared__ float sb[32];   // b1 slice
    int tid = threadIdx.x;
    int p = blockIdx.x & 3;
    if (tid < 128) sW[tid] = W2[p * 128 + tid];
    if (tid < 32) sb[tid] = b1[p * 32 + tid];
    __syncthreads();
    int node = (blockIdx.x >> 2) * 32 + (tid >> 3);
    if (node >= n) return;
    int lane = tid & 7;
    const uint* T = Hsu + (size_t)p * n * 8;
    float di = dinv[node];
    uint h0 = T[(node << 3) + lane];
    v2f lo = __builtin_amdgcn_cvt_pk_f32_fp8(h0, false);
    v2f hi = __builtin_amdgcn_cvt_pk_f32_fp8(h0, true);
    float acc0 = lo.x, acc1 = lo.y, acc2 = hi.x, acc3 = hi.y;  // self (pre-scaled by dinv)
    int2 od = offdeg[node];
    int j0 = od.x, j1 = od.x + od.y;
    int j = j0;
    for (; j + 8 <= j1; j += 8) {
        uint r[8];
#pragma unroll
        for (int k = 0; k < 8; ++k) r[k] = T[(ed[j + k] << 3) + lane];
#pragma unroll
        for (int k = 0; k < 8; ++k) {
            v2f l2 = __builtin_amdgcn_cvt_pk_f32_fp8(r[k], false);
            v2f h2 = __builtin_amdgcn_cvt_pk_f32_fp8(r[k], true);
            acc0 += l2.x; acc1 += l2.y; acc2 += h2.x; acc3 += h2.y;
        }
    }
    for (; j < j1; ++j) {
        uint rr = T[(ed[j] << 3) + lane];
        v2f l2 = __builtin_amdgcn_cvt_pk_f32_fp8(rr, false);
        v2f h2 = __builtin_amdgcn_cvt_pk_f32_fp8(rr, true);
        acc0 += l2.x; acc1 += l2.y; acc2 += h2.x; acc3 += h2.y;
    }
    int f = lane * 4;
    float v0 = di * acc0 + sb[f + 0];
    float v1 = di * acc1 + sb[f + 1];
    float v2 = di * acc2 + sb[f + 2];
    float v3 = di * acc3 + sb[f + 3];
    v0 = v0 >= 0.f ? v0 : 0.01f * v0;
    v1 = v1 >= 0.f ? v1 : 0.01f * v1;
    v2 = v2 >= 0.f ? v2 : 0.01f * v2;
    v3 = v3 >= 0.f ? v3 : 0.01f * v3;
    float a0 = v0 * sW[f * 4 + 0] + v1 * sW[(f + 1) * 4 + 0] + v2 * sW[(f + 2) * 4 + 0] + v3 * sW[(f + 3) * 4 + 0];
    float a1 = v0 * sW[f * 4 + 1] + v1 * sW[(f + 1) * 4 + 1] + v2 * sW[(f + 2) * 4 + 1] + v3 * sW[(f + 3) * 4 + 1];
    float a2 = v0 * sW[f * 4 + 2] + v1 * sW[(f + 1) * 4 + 2] + v2 * sW[(f + 2) * 4 + 2] + v3 * sW[(f + 3) * 4 + 2];
    float a3 = v0 * sW[f * 4 + 3] + v1 * sW[(f + 1) * 4 + 3] + v2 * sW[(f + 2) * 4 + 3] + v3 * sW[(f + 3) * 4 + 3];
#pragma unroll
    for (int o = 4; o >= 1; o >>= 1) {
        a0 += __shfl_xor(a0, o);
        a1 += __shfl_xor(a1, o);
        a2 += __shfl_xor(a2, o);
        a3 += __shfl_xor(a3, o);
    }
    if (lane == 0) zpart[(size_t)p * n + node] = make_float4(a0, a1, a2, a3);
}

// ---------------- reduce 4 partials -> zs = dinv*z; block 0 zeros psum/pcnt ----------------
__global__ __launch_bounds__(256) void k_zred(const float4* __restrict__ zpart,
                                              const float* __restrict__ dinv,
                                              float4* __restrict__ zs,
                                              float* __restrict__ psum,
                                              float* __restrict__ pcnt, int n) {
    int tid = threadIdx.x;
    if (blockIdx.x == 0) {
        if (tid < NG * 4) psum[tid] = 0.f;
        if (tid < NG) pcnt[tid] = 0.f;
    }
    int i = blockIdx.x * 256 + tid;
    if (i >= n) return;
    float4 a = zpart[i];
    float4 b = zpart[(size_t)n + i];
    float4 c = zpart[(size_t)2 * n + i];
    float4 d = zpart[(size_t)3 * n + i];
    float di = dinv[i];
    zs[i] = make_float4(di * (a.x + b.x + c.x + d.x), di * (a.y + b.y + c.y + d.y),
                        di * (a.z + b.z + c.z + d.z), di * (a.w + b.w + c.w + d.w));
}

// ---------------- layer-2 agg + mean-pool, EDGE-WISE, 2 blocks per bucket ----------------
__global__ __launch_bounds__(256) void k_pool2(const int* __restrict__ p1,
                                               const int* __restrict__ gcur,
                                               const float4* __restrict__ zs,
                                               const float* __restrict__ dinv,
                                               const int* __restrict__ batch,
                                               float* __restrict__ psum, float* __restrict__ pcnt,
                                               int n) {
    __shared__ float ls[NG * 4];
    __shared__ float lc[NG];
    __shared__ float dinvd[NPB];
    __shared__ int gl[NPB];
    int tid = threadIdx.x;
    int b = blockIdx.x >> 1;
    int half = blockIdx.x & 1;
    int node0 = b << 8;
    int node = node0 + tid;
    ls[tid] = 0.f;
    if (tid < NG) lc[tid] = 0.f;
    bool valid = node < n;
    float di = valid ? dinv[node] : 0.f;
    int g = valid ? batch[node] : -1;
    dinvd[tid] = di;
    gl[tid] = g;
    __syncthreads();
    float a0 = 0.f, a1 = 0.f, a2 = 0.f, a3 = 0.f;
    int cg = -1;
    if (half == 0 && valid) {
        float4 zv = zs[node];
        cg = g;
        a0 = di * zv.x; a1 = di * zv.y; a2 = di * zv.z; a3 = di * zv.w;
        atomicAdd(&lc[g], 1.f);
    }
    int base = b * CAPB;
    int cnt = gcur[b] - base;
    int mid = cnt >> 1;
    int s0 = base + (half ? mid : 0);
    int s1 = base + (half ? cnt : mid);
    for (int p = s0 + tid; p < s1; p += 1024) {
        int vv[4];
        float4 zb[4];
        int nb = 0;
#pragma unroll
        for (int k = 0; k < 4; ++k) {
            int q = p + k * 256;
            if (q < s1) vv[nb++] = p1[q];
        }
#pragma unroll
        for (int k = 0; k < 4; ++k)
            if (k < nb) zb[k] = zs[vv[k] & 0x1FFFF];
#pragma unroll
        for (int k = 0; k < 4; ++k) {
            if (k >= nb) continue;
            int dl = vv[k] >> 17;
            float w = dinvd[dl];
            int eg = gl[dl];
            if (eg != cg) {
                if (cg >= 0) {
                    atomicAdd(&ls[cg * 4 + 0], a0);
                    atomicAdd(&ls[cg * 4 + 1], a1);
                    atomicAdd(&ls[cg * 4 + 2], a2);
                    atomicAdd(&ls[cg * 4 + 3], a3);
                }
                cg = eg;
                a0 = a1 = a2 = a3 = 0.f;
            }
            a0 += w * zb[k].x; a1 += w * zb[k].y; a2 += w * zb[k].z; a3 += w * zb[k].w;
        }
    }
    if (cg >= 0) {
        atomicAdd(&ls[cg * 4 + 0], a0);
        atomicAdd(&ls[cg * 4 + 1], a1);
        atomicAdd(&ls[cg * 4 + 2], a2);
        atomicAdd(&ls[cg * 4 + 3], a3);
    }
    __syncthreads();
    atomicAdd(&psum[tid], ls[tid]);
    if (tid < NG) atomicAdd(&pcnt[tid], lc[tid]);
}

// ---------------- final: pooled = psum/cnt + b2; softmax over 4 ----------------
__global__ void k_final(const float* __restrict__ psum, const float* __restrict__ pcnt,
                        const float* __restrict__ b2, float* __restrict__ out) {
    int g = threadIdx.x;  // 64 threads
    float c = fmaxf(pcnt[g], 1.f);
    float inv = 1.f / c;
    float l0 = psum[g * 4 + 0] * inv + b2[0];
    float l1 = psum[g * 4 + 1] * inv + b2[1];
    float l2 = psum[g * 4 + 2] * inv + b2[2];
    float l3 = psum[g * 4 + 3] * inv + b2[3];
    float m = fmaxf(fmaxf(l0, l1), fmaxf(l2, l3));
    float e0 = expf(l0 - m), e1 = expf(l1 - m), e2 = expf(l2 - m), e3 = expf(l3 - m);
    float s = 1.f / (e0 + e1 + e2 + e3);
    *(float4*)&out[g * 4] = make_float4(e0 * s, e1 * s, e2 * s, e3 * s);
}

extern "C" void kernel_launch(void* const* d_in, const int* in_sizes, int n_in,
                              void* d_out, int out_size, void* d_ws, size_t ws_size,
                              hipStream_t stream) {
    const float* X = (const float*)d_in[0];
    const int* edge = (const int*)d_in[1];
    const int* batch = (const int*)d_in[2];
    const float* W1 = (const float*)d_in[3];
    const float* b1 = (const float*)d_in[4];
    const float* W2 = (const float*)d_in[5];
    const float* b2 = (const float*)d_in[6];
    float* out = (float*)d_out;
    const int n = in_sizes[2];      // 100000
    const int E = in_sizes[1] / 2;  // 1600000
    const int NBK = (n + NPB - 1) / NPB;  // 391

    // ws: Hs[n*32 uint] | p1[NBK*CAPB] | ed[NBK*CAPB] | zpart[4n float4] | zs[n float4]
    //   | dinv[n] | offdeg[n int2] | W1T[16384 short] | gcur[512] | psum[256] | pcnt[64]
    uint* Hs = (uint*)d_ws;
    int* p1 = (int*)(Hs + (size_t)n * 32);
    int* ed = p1 + (size_t)NBK * CAPB;
    float4* zpart = (float4*)(ed + (size_t)NBK * CAPB);
    float4* zs = zpart + (size_t)NPASS * n;
    float* dinv = (float*)(zs + n);
    int2* offdeg = (int2*)(dinv + n);
    short* W1T = (short*)(offdeg + n);
    int* gcur = (int*)(W1T + 16384);
    float* psum = (float*)(gcur + MAXBK);
    float* pcnt = psum + NG * 4;

    const int NP = (E + PCHUNK - 1) / PCHUNK;  // 391
    const int NGB = (n + 31) / 32;             // gather node-blocks per pass

    k_init<<<64, 256, 0, stream>>>(W1, W1T, gcur, NBK);
    k_part<<<NP, 256, 0, stream>>>(edge, gcur, p1, E, NBK);
    k_place<<<NBK, 256, 0, stream>>>(p1, gcur, ed, offdeg, dinv, n);

    k_gemm_mfma<<<(n + 127) / 128, 256, 0, stream>>>(X, W1T, dinv, (uchar_t*)Hs, n);

    k_gather<<<NGB * NPASS, 256, 0, stream>>>(Hs, offdeg, ed, dinv, b1, W2, zpart, n);
    k_zred<<<(n + 255) / 256, 256, 0, stream>>>(zpart, dinv, zs, psum, pcnt, n);

    k_pool2<<<NBK * 2, 256, 0, stream>>>(p1, gcur, zs, dinv, batch, psum, pcnt, n);
    k_final<<<1, 64, 0, stream>>>(psum, pcnt, b2, out);
}